// Round 18
// baseline (180.431 us; speedup 1.0000x reference)
//
#include <hip/hip_runtime.h>
#include <hip/hip_bf16.h>
#include <stdint.h>

#define S_LEN 2048
#define BATCH 4
#define NH    16
#define DH    64
#define DM    1024
#define MTOT  (BATCH*S_LEN)

typedef short bf16x8 __attribute__((ext_vector_type(8)));
typedef float f32x4 __attribute__((ext_vector_type(4)));
typedef uint32_t u32x4 __attribute__((ext_vector_type(4)));

__device__ __forceinline__ uint16_t f2bf(float f) {
  union { float f; uint32_t i; } c; c.f = f;
  uint32_t r = c.i + 0x7fffu + ((c.i >> 16) & 1u);
  return (uint16_t)(r >> 16);
}

__device__ __forceinline__ uint32_t cvt_pk_bf16(float a, float b) {
  uint32_t r;
  asm("v_cvt_pk_bf16_f32 %0, %1, %2" : "=v"(r) : "v"(a), "v"(b));
  return r;
}

__device__ __forceinline__ void async_copy16(void* lds, const void* g) {
  __builtin_amdgcn_global_load_lds(
      (const __attribute__((address_space(1))) void*)g,
      (__attribute__((address_space(3))) void*)lds, 16, 0, 0);
}

// ---------------- fp32 -> bf16 convert, all 5 tensors in one dispatch ----------------
__global__ __launch_bounds__(256) void cvt_all(const float* __restrict__ x,
                                               const float* __restrict__ wq,
                                               const float* __restrict__ wk,
                                               const float* __restrict__ wv,
                                               const float* __restrict__ wo,
                                               uint16_t* __restrict__ xb,
                                               uint16_t* __restrict__ wb) {
  const int blk = blockIdx.x;
  const float* src;
  uint16_t* dst;
  int n4, b0, nb;
  if (blk < 512) {
    src = x; dst = xb; n4 = MTOT * DM / 4; b0 = blk; nb = 512;
  } else {
    const int sel = (blk - 512) >> 6;
    src = sel == 0 ? wq : sel == 1 ? wk : sel == 2 ? wv : wo;
    dst = wb + (size_t)sel * DM * DM;
    n4 = DM * DM / 4; b0 = (blk - 512) & 63; nb = 64;
  }
  const int stride = nb * 256;
  for (int i = b0 * 256 + threadIdx.x; i < n4; i += stride) {
    float4 v = ((const float4*)src)[i];
    ushort4 o;
    o.x = f2bf(v.x); o.y = f2bf(v.y); o.z = f2bf(v.z); o.w = f2bf(v.w);
    ((ushort4*)dst)[i] = o;
  }
}

// ---------------- GEMM: C[m][n] = sum_k A[m][k]*Bw[n][k], tile 128 x BN -------------
// MODE 0 (BN=128): n in [0,3072); tsel = bn>>10 selects q/k/v.
//   tsel<2: RoPE fused in-epilogue; tsel==2: V transposed+sigma via LDS.
// MODE 1 (BN=64): write fp32 [M][DM].  3-stage LDS pipeline, counted vmcnt.
template<int MODE, int BN>
__global__ __launch_bounds__(256) void gemm_bt(const uint16_t* __restrict__ A,
                                               const uint16_t* __restrict__ Bw,
                                               void* __restrict__ outp,
                                               uint16_t* __restrict__ vtp,
                                               const int* __restrict__ pos) {
  constexpr int K = DM;
  constexpr int NT = K / 32;       // 32 K-tiles
  constexpr int WC = BN / 2;       // per-wave output cols
  constexpr int NF = WC / 16;      // B fragments per wave
  constexpr int ASZ = 3 * 128 * 32;
  constexpr int BSZ = 3 * BN * 32;
  __shared__ __align__(16) uint16_t sh[ASZ + BSZ];
  uint16_t* lA = sh;
  uint16_t* lB = sh + ASZ;
  const int tid = threadIdx.x;
  const int w = tid >> 6, lane = tid & 63;
  const int l15 = lane & 15, lhi = lane >> 4;
  const int wr = w >> 1, wc = w & 1;

  // XCD-aware block swizzle (grids are %8==0)
  const int nx = gridDim.x, nwg = nx * gridDim.y;
  const int flat = blockIdx.y * nx + blockIdx.x;
  const int wg = (flat & 7) * (nwg >> 3) + (flat >> 3);
  const int bm = (wg / nx) * 128, bn = (wg % nx) * BN;

  const int srow = tid >> 2;            // 64 rows covered per 256 threads
  const int cb = (tid & 3) * 16;        // byte offset within 64B row

  auto stage = [&](int b, int t) {
    const int k0 = t * 32;
#pragma unroll
    for (int i = 0; i < 2; ++i)
      async_copy16((char*)(lA + b * 128 * 32) + i * 4096 + w * 1024,
                   (const char*)A + ((size_t)(bm + i * 64 + srow) * K + k0) * 2 + cb);
#pragma unroll
    for (int i = 0; i < BN / 64; ++i)
      async_copy16((char*)(lB + b * BN * 32) + i * 4096 + w * 1024,
                   (const char*)Bw + ((size_t)(bn + i * 64 + srow) * K + k0) * 2 + cb);
  };

  f32x4 acc[4][NF] = {};

  stage(0, 0);
  stage(1, 1);
  if constexpr (BN == 128) asm volatile("s_waitcnt vmcnt(4)" ::: "memory");
  else                     asm volatile("s_waitcnt vmcnt(3)" ::: "memory");
  __builtin_amdgcn_s_barrier();
  __builtin_amdgcn_sched_barrier(0);

  int cur = 0;
  for (int t = 0; t < NT; ++t) {
    const bool pre = (t + 2 < NT);
    int bnext = cur + 2; if (bnext >= 3) bnext -= 3;
    if (pre) stage(bnext, t + 2);

    bf16x8 af[4], bfr[NF];
#pragma unroll
    for (int mf = 0; mf < 4; ++mf)
      af[mf] = *(const bf16x8*)((const char*)(lA + cur * 128 * 32) +
                                (wr * 64 + mf * 16 + l15) * 64 + lhi * 16);
#pragma unroll
    for (int nf = 0; nf < NF; ++nf)
      bfr[nf] = *(const bf16x8*)((const char*)(lB + cur * BN * 32) +
                                 (wc * WC + nf * 16 + l15) * 64 + lhi * 16);
    __builtin_amdgcn_s_setprio(1);
#pragma unroll
    for (int mf = 0; mf < 4; ++mf)
#pragma unroll
      for (int nf = 0; nf < NF; ++nf)
        acc[mf][nf] = __builtin_amdgcn_mfma_f32_16x16x32_bf16(af[mf], bfr[nf], acc[mf][nf], 0, 0, 0);
    __builtin_amdgcn_s_setprio(0);

    if (pre) {
      if constexpr (BN == 128) asm volatile("s_waitcnt vmcnt(4)" ::: "memory");
      else                     asm volatile("s_waitcnt vmcnt(3)" ::: "memory");
    } else {
      asm volatile("s_waitcnt vmcnt(0)" ::: "memory");
    }
    __builtin_amdgcn_s_barrier();
    __builtin_amdgcn_sched_barrier(0);
    cur = cur + 1 == 3 ? 0 : cur + 1;
  }

  if (MODE == 0) {
    const int tsel = bn >> 10;  // uniform per block
    if (tsel < 2) {
      uint16_t* out = (uint16_t*)outp + (size_t)tsel * ((size_t)MTOT * DM);
      // RoPE fused: lane pair (even d, odd d) exchanges via shfl_xor(.,1).
      const float l2t_32 = 0.41524101186092074f;            // log2(10000)/32
      const float qsc = tsel == 0 ? 0.18033688011112042f : 1.0f;  // 0.125*log2e
#pragma unroll
      for (int mf = 0; mf < 4; ++mf) {
        float ps[4];
#pragma unroll
        for (int r = 0; r < 4; ++r) {
          const int m = bm + wr * 64 + mf * 16 + lhi * 4 + r;
          ps[r] = (float)pos[m & (S_LEN - 1)];
        }
#pragma unroll
        for (int nf = 0; nf < NF; ++nf) {
          const int n = bn + wc * WC + nf * 16 + l15;
          const int e = n & 1023;
          const int h = e >> 6, d = e & 63;
          const float inv = __builtin_amdgcn_exp2f(-(float)(d >> 1) * l2t_32);
#pragma unroll
          for (int r = 0; r < 4; ++r) {
            const int m = bm + wr * 64 + mf * 16 + lhi * 4 + r;
            const int b = m >> 11, s = m & (S_LEN - 1);
            const float v = acc[mf][nf][r];
            const float p = __shfl_xor(v, 1);
            const float ang = ps[r] * inv;
            const float cs = __cosf(ang) * qsc, sn = __sinf(ang) * qsc;
            const float val = (l15 & 1) ? (p * sn + v * cs) : (v * cs - p * sn);
            out[(((size_t)(b * NH + h) * S_LEN + s) << 6) + d] = f2bf(val);
          }
        }
      }
    } else {
      // V: LDS transpose -> sigma-permuted [bh][d][s] writes (coalesced).
      uint16_t* T = sh;
#pragma unroll
      for (int mf = 0; mf < 4; ++mf)
#pragma unroll
        for (int nf = 0; nf < NF; ++nf) {
          const int n = wc * WC + nf * 16 + l15;
          const int m0 = wr * 64 + mf * 16 + lhi * 4;
          uint32_t lo = cvt_pk_bf16(acc[mf][nf][0], acc[mf][nf][1]);
          uint32_t hi = cvt_pk_bf16(acc[mf][nf][2], acc[mf][nf][3]);
          *(uint2*)(T + n * 136 + m0) = make_uint2(lo, hi);
        }
      __syncthreads();
      const int b = bm >> 11, s0 = bm & (S_LEN - 1);
      const int ebase = bn & 1023;
      for (int idx = tid; idx < 2048; idx += 256) {
        const int n = idx >> 4;          // col 0..127
        const int j0 = (idx & 15) * 8;   // out s-offset 0..120
        const int oa_ = j0 & 63;
        const int pa_ = (j0 & 64) | (oa_ & 0x23) | ((oa_ & 4) << 2) |
                        ((oa_ & 16) >> 1) | ((oa_ & 8) >> 1);
        const int ob_ = (j0 + 4) & 63;
        const int pb_ = (j0 & 64) | (ob_ & 0x23) | ((ob_ & 4) << 2) |
                        ((ob_ & 16) >> 1) | ((ob_ & 8) >> 1);
        const uint2 va = *(const uint2*)(T + n * 136 + pa_);
        const uint2 vb2 = *(const uint2*)(T + n * 136 + pb_);
        const int e = ebase + n;
        const int hg = e >> 6, d = e & 63;
        uint16_t* dst = vtp + ((size_t)(b * NH + hg) * DH + d) * S_LEN + s0 + j0;
        uint4 o4; o4.x = va.x; o4.y = va.y; o4.z = vb2.x; o4.w = vb2.y;
        *(uint4*)dst = o4;
      }
    }
  } else {
    float* out = (float*)outp;  // [M][DM]
#pragma unroll
    for (int mf = 0; mf < 4; ++mf)
#pragma unroll
      for (int nf = 0; nf < NF; ++nf)
#pragma unroll
        for (int r = 0; r < 4; ++r) {
          const int m = bm + wr * 64 + mf * 16 + lhi * 4 + r;
          const int n = bn + wc * WC + nf * 16 + l15;
          out[(size_t)m * DM + n] = acc[mf][nf][r];
        }
  }
}

// ---------------- causal flash attention (256 thr, 64-row q-tiles, KVB=64) -----------
// q,k: [BH][S][64] bf16 (q pre-scaled); vt: [BH][64][S] bf16 sigma-permuted;
// o: [B,S,DM] bf16. 4 waves/block, 16 q-rows/wave. Block p processes q-tiles
// {31-p, p} sequentially (uniform 33 KV-iterations). KV tile 64 double-buffered
// (32 KB LDS); low VGPR (sf[4]+oa[4]) -> 5 blocks/CU for drain overlap.
__global__ __launch_bounds__(256, 5) void attn_kernel(const uint16_t* __restrict__ q,
                                                      const uint16_t* __restrict__ kk,
                                                      const uint16_t* __restrict__ vt,
                                                      uint16_t* __restrict__ o) {
  const int bh = blockIdx.y;
  const int p = blockIdx.x;  // q-tiles {31-p (heavy, first), p}
  const int tid = threadIdx.x;
  const int w = __builtin_amdgcn_readfirstlane(tid >> 6);  // 0..3
  const int lane = tid & 63;
  const int l15 = lane & 15, lhi = lane >> 4;
  const uint16_t* qb = q + (size_t)bh * S_LEN * DH;
  const uint16_t* kb = kk + (size_t)bh * S_LEN * DH;
  const uint16_t* vb = vt + (size_t)bh * DH * S_LEN;

  __shared__ uint16_t lK[2][64 * 64];  // [kv 64][d 64], 128B rows
  __shared__ uint16_t lV[2][64 * 64];  // [d 64][kv 64], 128B rows

  // staging: thread covers rows tid>>3 and 32+(tid>>3); slot = tid&7 (16B)
  const int srow = tid >> 3;
  const int sl = tid & 7;

  auto stage = [&](int b, int t) {
    const int k0 = t * 64;
#pragma unroll
    for (int i = 0; i < 2; ++i) {
      const int kr = i * 32 + srow;
      const int scK = sl ^ (kr & 7);
      async_copy16((char*)lK[b] + i * 4096 + (tid & 255) * 16,
                   (const char*)kb + ((size_t)(k0 + kr) * 64 + scK * 8) * 2);
      const int scV = sl ^ (kr & 7);
      async_copy16((char*)lV[b] + i * 4096 + (tid & 255) * 16,
                   (const char*)vb + ((size_t)kr * S_LEN + k0 + scV * 8) * 2);
    }
  };

  stage(0, 0);
  asm volatile("s_waitcnt vmcnt(0)" ::: "memory");
  __syncthreads();

  int cur = 0;
  const int b_out = bh >> 4, h_out = bh & 15;

  for (int s = 0; s < 2; ++s) {
    const int jq = s ? p : (31 - p);
    const int q0 = jq * 64 + w * 16;

    bf16x8 qf[2];
#pragma unroll
    for (int c = 0; c < 2; ++c)
      qf[c] = *(const bf16x8*)(qb + (size_t)(q0 + l15) * DH + c * 32 + lhi * 8);

    f32x4 oa[4] = {};
    float mr = -1e30f, lr = 0.f;

    const int nt = jq + 1;
    for (int t = 0; t < nt; ++t) {
      if (t + 1 < nt) stage(cur ^ 1, t + 1);
      else if (s == 0) stage(cur ^ 1, 0);  // prefetch next segment's tile 0

      const bool diag = (t == jq);
      const int fMf = diag ? w : 3;        // last f with real MFMA
      const int fE  = diag ? (w | 1) : 3;  // last f carried into P
      const int cE  = diag ? (w >> 1) : 1; // last PV chunk

      // swapped QK^T: lane owns q-row q0+l15; kv = t*64 + f*16 + lhi*4 + r
      f32x4 sf[4];
      __builtin_amdgcn_s_setprio(1);
#pragma unroll
      for (int f = 0; f < 4; ++f) {
        f32x4 z = {0.f, 0.f, 0.f, 0.f};
        if (f <= fMf) {
          const int kr = f * 16 + l15;
          const char* kbase = (const char*)lK[cur] + kr * 128;
          bf16x8 kf0 = *(const bf16x8*)(kbase + ((lhi ^ (kr & 7)) << 4));
          bf16x8 kf1 = *(const bf16x8*)(kbase + (((4 + lhi) ^ (kr & 7)) << 4));
          z = __builtin_amdgcn_mfma_f32_16x16x32_bf16(kf0, qf[0], z, 0, 0, 0);
          z = __builtin_amdgcn_mfma_f32_16x16x32_bf16(kf1, qf[1], z, 0, 0, 0);
        }
        sf[f] = z;
      }
      __builtin_amdgcn_s_setprio(0);

      if (diag) {
        const int qrow = w * 16 + l15;  // tile-relative
#pragma unroll
        for (int f = 0; f < 4; ++f)
          if (f <= fE)
#pragma unroll
            for (int r = 0; r < 4; ++r) {
              const int kv = f * 16 + lhi * 4 + r;
              if (kv > qrow) sf[f][r] = -1e30f;
            }
      }

      // row max: in-lane, then combine the 4 lanes sharing this q-row
      float pm = -1e30f;
#pragma unroll
      for (int f = 0; f < 4; ++f)
        if (f <= fE)
#pragma unroll
          for (int r = 0; r < 4; ++r) pm = fmaxf(pm, sf[f][r]);
      pm = fmaxf(pm, __shfl_xor(pm, 16));
      pm = fmaxf(pm, __shfl_xor(pm, 32));

      if (!__all(pm <= mr + 8.0f)) {  // T13 defer-max
        const float mn = fmaxf(mr, pm);
        const float resc = __builtin_amdgcn_exp2f(mr - mn);
        mr = mn;
        lr *= resc;
#pragma unroll
        for (int r = 0; r < 4; ++r) {
          const float rb = __shfl(resc, (lhi << 2) + r);
#pragma unroll
          for (int df = 0; df < 4; ++df) oa[df][r] *= rb;
        }
      }

      float rs = 0.f;
#pragma unroll
      for (int f = 0; f < 4; ++f)
        if (f <= fE)
#pragma unroll
          for (int r = 0; r < 4; ++r) {
            const float pv = __builtin_amdgcn_exp2f(sf[f][r] - mr);
            sf[f][r] = pv;
            rs += pv;
          }
      rs += __shfl_xor(rs, 16);
      rs += __shfl_xor(rs, 32);
      lr += rs;

      // PV: P -> A-fragments in-register (V sigma-permuted to match)
#pragma unroll
      for (int c = 0; c < 2; ++c) {
        if (c <= cE) {
          u32x4 u;
          u.x = cvt_pk_bf16(sf[2 * c][0], sf[2 * c][1]);
          u.y = cvt_pk_bf16(sf[2 * c][2], sf[2 * c][3]);
          u.z = cvt_pk_bf16(sf[2 * c + 1][0], sf[2 * c + 1][1]);
          u.w = cvt_pk_bf16(sf[2 * c + 1][2], sf[2 * c + 1][3]);
          bf16x8 pa = __builtin_bit_cast(bf16x8, u);
          __builtin_amdgcn_s_setprio(1);
#pragma unroll
          for (int df = 0; df < 4; ++df) {
            const int vr = df * 16 + l15;
            bf16x8 vf = *(const bf16x8*)((const char*)lV[cur] + vr * 128 +
                                         (((c * 4 + lhi) ^ (vr & 7)) << 4));
            oa[df] = __builtin_amdgcn_mfma_f32_16x16x32_bf16(pa, vf, oa[df], 0, 0, 0);
          }
          __builtin_amdgcn_s_setprio(0);
        }
      }

      asm volatile("s_waitcnt vmcnt(0)" ::: "memory");
      __syncthreads();
      cur ^= 1;
    }

    // segment epilogue
    float inv[4];
#pragma unroll
    for (int r = 0; r < 4; ++r)
      inv[r] = __builtin_amdgcn_rcpf(__shfl(lr, (lhi << 2) + r));
#pragma unroll
    for (int df = 0; df < 4; ++df)
#pragma unroll
      for (int r = 0; r < 4; ++r) {
        const int srow_o = q0 + lhi * 4 + r;
        const float val = oa[df][r] * inv[r];
        const int d = df * 16 + l15;
        o[((size_t)(b_out * S_LEN + srow_o)) * DM + h_out * 64 + d] = f2bf(val);
      }
  }
}

extern "C" void kernel_launch(void* const* d_in, const int* in_sizes, int n_in,
                              void* d_out, int out_size, void* d_ws, size_t ws_size,
                              hipStream_t stream) {
  const float* x = (const float*)d_in[0];
  const float* Wq = (const float*)d_in[1];
  const float* Wk = (const float*)d_in[2];
  const float* Wv = (const float*)d_in[3];
  const float* Wo = (const float*)d_in[4];
  const int* pos = (const int*)d_in[5];

  char* ws = (char*)d_ws;
  size_t off = 0;
  auto alloc = [&](size_t bytes) {
    void* p = ws + off;
    off += (bytes + 255) & ~(size_t)255;
    return p;
  };
  uint16_t* xb    = (uint16_t*)alloc((size_t)MTOT * DM * 2);      // also reused as attn output
  uint16_t* wqkvb = (uint16_t*)alloc((size_t)4 * DM * DM * 2);    // contiguous Wq|Wk|Wv|Wo
  uint16_t* qkb   = (uint16_t*)alloc((size_t)2 * MTOT * DM * 2);  // contiguous q|k
  uint16_t* vtb   = (uint16_t*)alloc((size_t)MTOT * DM * 2);      // v, transposed+sigma
  uint16_t* wob = wqkvb + (size_t)3 * DM * DM;
  uint16_t* qb = qkb;
  uint16_t* kbuf = qkb + (size_t)MTOT * DM;
  uint16_t* attnb = xb;  // reuse: x (bf16) dead after QKV projection

  cvt_all<<<768, 256, 0, stream>>>(x, Wq, Wk, Wv, Wo, xb, wqkvb);

  // fused QKV projection + RoPE + V-transpose: N = 3072
  gemm_bt<0, 128><<<dim3(24, MTOT / 128), 256, 0, stream>>>(xb, wqkvb, qkb, vtb, pos);

  attn_kernel<<<dim3(16, 64), 256, 0, stream>>>(qb, kbuf, vtb, attnb);

  // output projection: 128x64 tiles -> 1024 blocks (4/CU) for TLP
  gemm_bt<1, 64><<<dim3(16, MTOT / 128), 256, 0, stream>>>(attnb, wob, d_out, nullptr, nullptr);
}

// Round 19
// 167.803 us; speedup vs baseline: 1.0753x; 1.0753x over previous
//
#include <hip/hip_runtime.h>
#include <hip/hip_bf16.h>
#include <stdint.h>

#define S_LEN 2048
#define BATCH 4
#define NH    16
#define DH    64
#define DM    1024
#define MTOT  (BATCH*S_LEN)

typedef short bf16x8 __attribute__((ext_vector_type(8)));
typedef float f32x4 __attribute__((ext_vector_type(4)));
typedef uint32_t u32x4 __attribute__((ext_vector_type(4)));

__device__ __forceinline__ uint16_t f2bf(float f) {
  union { float f; uint32_t i; } c; c.f = f;
  uint32_t r = c.i + 0x7fffu + ((c.i >> 16) & 1u);
  return (uint16_t)(r >> 16);
}

__device__ __forceinline__ uint32_t cvt_pk_bf16(float a, float b) {
  uint32_t r;
  asm("v_cvt_pk_bf16_f32 %0, %1, %2" : "=v"(r) : "v"(a), "v"(b));
  return r;
}

__device__ __forceinline__ void async_copy16(void* lds, const void* g) {
  __builtin_amdgcn_global_load_lds(
      (const __attribute__((address_space(1))) void*)g,
      (__attribute__((address_space(3))) void*)lds, 16, 0, 0);
}

// ---------------- fp32 -> bf16 convert, all 5 tensors in one dispatch ----------------
// blocks [0,512): x (n4=2M); blocks [512+64*s, 512+64*(s+1)): weight s (n4=256K).
__global__ __launch_bounds__(256) void cvt_all(const float* __restrict__ x,
                                               const float* __restrict__ wq,
                                               const float* __restrict__ wk,
                                               const float* __restrict__ wv,
                                               const float* __restrict__ wo,
                                               uint16_t* __restrict__ xb,
                                               uint16_t* __restrict__ wb) {
  const int blk = blockIdx.x;
  const float* src;
  uint16_t* dst;
  int n4, b0, nb;
  if (blk < 512) {
    src = x; dst = xb; n4 = MTOT * DM / 4; b0 = blk; nb = 512;
  } else {
    const int sel = (blk - 512) >> 6;
    src = sel == 0 ? wq : sel == 1 ? wk : sel == 2 ? wv : wo;
    dst = wb + (size_t)sel * DM * DM;
    n4 = DM * DM / 4; b0 = (blk - 512) & 63; nb = 64;
  }
  const int stride = nb * 256;
  for (int i = b0 * 256 + threadIdx.x; i < n4; i += stride) {
    float4 v = ((const float4*)src)[i];
    ushort4 o;
    o.x = f2bf(v.x); o.y = f2bf(v.y); o.z = f2bf(v.z); o.w = f2bf(v.w);
    ((ushort4*)dst)[i] = o;
  }
}

// ---------------- GEMM: C[m][n] = sum_k A[m][k]*Bw[n][k], tile 128 x BN -------------
// MODE 0 (BN=128): n in [0,3072); tsel = bn>>10 selects q/k/v.
//   tsel<2: RoPE fused in-epilogue (q also pre-scaled by 0.125*log2e),
//           bf16 scatter to [tsel][B,H,S,DH].
//   tsel==2: V written transposed+sigma-permuted to vtp via LDS transpose
//            (staging LDS reused post-K-loop; coalesced 16B stores along s).
// MODE 1 (BN=64): write fp32 [M][DM].  3-stage LDS pipeline, counted vmcnt.
template<int MODE, int BN>
__global__ __launch_bounds__(256) void gemm_bt(const uint16_t* __restrict__ A,
                                               const uint16_t* __restrict__ Bw,
                                               void* __restrict__ outp,
                                               uint16_t* __restrict__ vtp,
                                               const int* __restrict__ pos) {
  constexpr int K = DM;
  constexpr int NT = K / 32;       // 32 K-tiles
  constexpr int WC = BN / 2;       // per-wave output cols
  constexpr int NF = WC / 16;      // B fragments per wave
  constexpr int ASZ = 3 * 128 * 32;
  constexpr int BSZ = 3 * BN * 32;
  __shared__ __align__(16) uint16_t sh[ASZ + BSZ];
  uint16_t* lA = sh;
  uint16_t* lB = sh + ASZ;
  const int tid = threadIdx.x;
  const int w = tid >> 6, lane = tid & 63;
  const int l15 = lane & 15, lhi = lane >> 4;
  const int wr = w >> 1, wc = w & 1;

  // XCD-aware block swizzle (grids are %8==0)
  const int nx = gridDim.x, nwg = nx * gridDim.y;
  const int flat = blockIdx.y * nx + blockIdx.x;
  const int wg = (flat & 7) * (nwg >> 3) + (flat >> 3);
  const int bm = (wg / nx) * 128, bn = (wg % nx) * BN;

  const int srow = tid >> 2;            // 64 rows covered per 256 threads
  const int cb = (tid & 3) * 16;        // byte offset within 64B row

  auto stage = [&](int b, int t) {
    const int k0 = t * 32;
#pragma unroll
    for (int i = 0; i < 2; ++i)
      async_copy16((char*)(lA + b * 128 * 32) + i * 4096 + w * 1024,
                   (const char*)A + ((size_t)(bm + i * 64 + srow) * K + k0) * 2 + cb);
#pragma unroll
    for (int i = 0; i < BN / 64; ++i)
      async_copy16((char*)(lB + b * BN * 32) + i * 4096 + w * 1024,
                   (const char*)Bw + ((size_t)(bn + i * 64 + srow) * K + k0) * 2 + cb);
  };

  f32x4 acc[4][NF] = {};

  stage(0, 0);
  stage(1, 1);
  if constexpr (BN == 128) asm volatile("s_waitcnt vmcnt(4)" ::: "memory");
  else                     asm volatile("s_waitcnt vmcnt(3)" ::: "memory");
  __builtin_amdgcn_s_barrier();
  __builtin_amdgcn_sched_barrier(0);

  int cur = 0;
  for (int t = 0; t < NT; ++t) {
    const bool pre = (t + 2 < NT);
    int bnext = cur + 2; if (bnext >= 3) bnext -= 3;
    if (pre) stage(bnext, t + 2);

    bf16x8 af[4], bfr[NF];
#pragma unroll
    for (int mf = 0; mf < 4; ++mf)
      af[mf] = *(const bf16x8*)((const char*)(lA + cur * 128 * 32) +
                                (wr * 64 + mf * 16 + l15) * 64 + lhi * 16);
#pragma unroll
    for (int nf = 0; nf < NF; ++nf)
      bfr[nf] = *(const bf16x8*)((const char*)(lB + cur * BN * 32) +
                                 (wc * WC + nf * 16 + l15) * 64 + lhi * 16);
    __builtin_amdgcn_s_setprio(1);
#pragma unroll
    for (int mf = 0; mf < 4; ++mf)
#pragma unroll
      for (int nf = 0; nf < NF; ++nf)
        acc[mf][nf] = __builtin_amdgcn_mfma_f32_16x16x32_bf16(af[mf], bfr[nf], acc[mf][nf], 0, 0, 0);
    __builtin_amdgcn_s_setprio(0);

    if (pre) {
      if constexpr (BN == 128) asm volatile("s_waitcnt vmcnt(4)" ::: "memory");
      else                     asm volatile("s_waitcnt vmcnt(3)" ::: "memory");
    } else {
      asm volatile("s_waitcnt vmcnt(0)" ::: "memory");
    }
    __builtin_amdgcn_s_barrier();
    __builtin_amdgcn_sched_barrier(0);
    cur = cur + 1 == 3 ? 0 : cur + 1;
  }

  if (MODE == 0) {
    const int tsel = bn >> 10;  // uniform per block
    if (tsel < 2) {
      uint16_t* out = (uint16_t*)outp + (size_t)tsel * ((size_t)MTOT * DM);
      // RoPE fused: lane pair (even d, odd d) exchanges via shfl_xor(.,1).
      const float l2t_32 = 0.41524101186092074f;            // log2(10000)/32
      const float qsc = tsel == 0 ? 0.18033688011112042f : 1.0f;  // 0.125*log2e
#pragma unroll
      for (int mf = 0; mf < 4; ++mf) {
        float ps[4];
#pragma unroll
        for (int r = 0; r < 4; ++r) {
          const int m = bm + wr * 64 + mf * 16 + lhi * 4 + r;
          ps[r] = (float)pos[m & (S_LEN - 1)];
        }
#pragma unroll
        for (int nf = 0; nf < NF; ++nf) {
          const int n = bn + wc * WC + nf * 16 + l15;
          const int e = n & 1023;
          const int h = e >> 6, d = e & 63;
          const float inv = __builtin_amdgcn_exp2f(-(float)(d >> 1) * l2t_32);
#pragma unroll
          for (int r = 0; r < 4; ++r) {
            const int m = bm + wr * 64 + mf * 16 + lhi * 4 + r;
            const int b = m >> 11, s = m & (S_LEN - 1);
            const float v = acc[mf][nf][r];
            const float p = __shfl_xor(v, 1);
            const float ang = ps[r] * inv;
            const float cs = __cosf(ang) * qsc, sn = __sinf(ang) * qsc;
            const float val = (l15 & 1) ? (p * sn + v * cs) : (v * cs - p * sn);
            out[(((size_t)(b * NH + h) * S_LEN + s) << 6) + d] = f2bf(val);
          }
        }
      }
    } else {
      // V: LDS transpose -> sigma-permuted [bh][d][s] writes (coalesced).
      // T[n][m], n=block col (0..127), m=block row (0..127), stride 136.
      uint16_t* T = sh;
#pragma unroll
      for (int mf = 0; mf < 4; ++mf)
#pragma unroll
        for (int nf = 0; nf < NF; ++nf) {
          const int n = wc * WC + nf * 16 + l15;
          const int m0 = wr * 64 + mf * 16 + lhi * 4;
          uint32_t lo = cvt_pk_bf16(acc[mf][nf][0], acc[mf][nf][1]);
          uint32_t hi = cvt_pk_bf16(acc[mf][nf][2], acc[mf][nf][3]);
          *(uint2*)(T + n * 136 + m0) = make_uint2(lo, hi);
        }
      __syncthreads();
      const int b = bm >> 11, s0 = bm & (S_LEN - 1);
      const int ebase = bn & 1023;
      for (int idx = tid; idx < 2048; idx += 256) {
        const int n = idx >> 4;          // col 0..127
        const int j0 = (idx & 15) * 8;   // out s-offset 0..120
        // sigma-inverse: j -> source m (low 2 bits preserved -> 4-elem runs)
        const int oa_ = j0 & 63;
        const int pa_ = (j0 & 64) | (oa_ & 0x23) | ((oa_ & 4) << 2) |
                        ((oa_ & 16) >> 1) | ((oa_ & 8) >> 1);
        const int ob_ = (j0 + 4) & 63;
        const int pb_ = (j0 & 64) | (ob_ & 0x23) | ((ob_ & 4) << 2) |
                        ((ob_ & 16) >> 1) | ((ob_ & 8) >> 1);
        const uint2 va = *(const uint2*)(T + n * 136 + pa_);
        const uint2 vb2 = *(const uint2*)(T + n * 136 + pb_);
        const int e = ebase + n;
        const int hg = e >> 6, d = e & 63;
        uint16_t* dst = vtp + ((size_t)(b * NH + hg) * DH + d) * S_LEN + s0 + j0;
        uint4 o4; o4.x = va.x; o4.y = va.y; o4.z = vb2.x; o4.w = vb2.y;
        *(uint4*)dst = o4;
      }
    }
  } else {
    float* out = (float*)outp;  // [M][DM]
#pragma unroll
    for (int mf = 0; mf < 4; ++mf)
#pragma unroll
      for (int nf = 0; nf < NF; ++nf)
#pragma unroll
        for (int r = 0; r < 4; ++r) {
          const int m = bm + wr * 64 + mf * 16 + lhi * 4 + r;
          const int n = bn + wc * WC + nf * 16 + l15;
          out[(size_t)m * DM + n] = acc[mf][nf][r];
        }
  }
}

// ---------------- causal flash attention (joint-sweep pairs, in-register P) ----------
// q,k: [BH][S][64] bf16 (q pre-scaled); vt: [BH][64][S] bf16 sigma-permuted;
// o: [B,S,DM] bf16. 512 threads = 8 waves. Block p serves q-tiles
// {jA=15-p, jB=p} (128 rows each) in ONE KV sweep of nt=16-p tiles: each
// staged tile feeds frag A always and frag B while t<=p. Compute is uniform
// (17 frag-iterations per block for every p); staging is 16-p tiles.
// Grid 8x64 = 512 blocks = 2/CU (64 KB LDS) -> drain overlap retained.
__global__ __launch_bounds__(512, 2) void attn_kernel(const uint16_t* __restrict__ q,
                                                      const uint16_t* __restrict__ kk,
                                                      const uint16_t* __restrict__ vt,
                                                      uint16_t* __restrict__ o) {
  const int bh = blockIdx.y;
  const int p = blockIdx.x;  // jA = 15-p (heavy), jB = p
  const int jA = 15 - p, jB = p;
  const int tid = threadIdx.x;
  const int w = __builtin_amdgcn_readfirstlane(tid >> 6);
  const int lane = tid & 63;
  const int l15 = lane & 15, lhi = lane >> 4;
  const uint16_t* qb = q + (size_t)bh * S_LEN * DH;
  const uint16_t* kb = kk + (size_t)bh * S_LEN * DH;
  const uint16_t* vb = vt + (size_t)bh * DH * S_LEN;

  __shared__ uint16_t lK[2][128 * 64];  // [kv 128][d 64], 128B rows
  __shared__ uint16_t lV[2][64 * 128];  // [d 64][kv 128], 256B rows

  const int krow_l = lane >> 3;
  const int scK = (lane & 7) ^ krow_l;
  const int vrow_l = lane >> 4;

  auto stage = [&](int b, int t) {
    const int k0 = t * 128;
#pragma unroll
    for (int i = 0; i < 2; ++i) {
      const int krow = w * 16 + i * 8 + krow_l;
      async_copy16((char*)lK[b] + w * 2048 + i * 1024 + lane * 16,
                   (const char*)kb + ((size_t)(k0 + krow) * 64 + scK * 8) * 2);
      const int vd = w * 8 + i * 4 + vrow_l;
      const int scV = (lane & 15) ^ (vd & 15);
      async_copy16((char*)lV[b] + w * 2048 + i * 1024 + lane * 16,
                   (const char*)vb + ((size_t)vd * S_LEN + k0 + scV * 8) * 2);
    }
  };

  stage(0, 0);
  asm volatile("s_waitcnt vmcnt(0)" ::: "memory");
  __syncthreads();

  int cur = 0;
  const int b_out = bh >> 4, h_out = bh & 15;

  bf16x8 qf[2][2];
#pragma unroll
  for (int fr = 0; fr < 2; ++fr) {
    const int q0 = (fr ? jB : jA) * 128 + w * 16;
#pragma unroll
    for (int c = 0; c < 2; ++c)
      qf[fr][c] = *(const bf16x8*)(qb + (size_t)(q0 + l15) * DH + c * 32 + lhi * 8);
  }

  f32x4 oa[2][4] = {};
  float mr[2] = {-1e30f, -1e30f}, lr[2] = {0.f, 0.f};

  const int nt = jA + 1;  // 16 - p tiles
  for (int t = 0; t < nt; ++t) {
    if (t + 1 < nt) stage(cur ^ 1, t + 1);

#pragma unroll
    for (int fr = 0; fr < 2; ++fr) {
      if (fr == 1 && t > jB) continue;     // frag B done (uniform branch)
      const int jq = fr ? jB : jA;
      const bool diag = (t == jq);
      const int fMf = diag ? w : 7;        // last f with real MFMA
      const int fE  = diag ? (w | 1) : 7;  // last f carried into P
      const int cE  = diag ? (w >> 1) : 3; // last PV chunk

      // swapped QK^T: lane owns q-row jq*128+w*16+l15; kv = t*128+f*16+lhi*4+r
      f32x4 sf[8];
      __builtin_amdgcn_s_setprio(1);
#pragma unroll
      for (int f = 0; f < 8; ++f) {
        f32x4 z = {0.f, 0.f, 0.f, 0.f};
        if (f <= fMf) {
          const int kr = f * 16 + l15;
          const char* kbase = (const char*)lK[cur] + kr * 128;
          bf16x8 kf0 = *(const bf16x8*)(kbase + ((lhi ^ (kr & 7)) << 4));
          bf16x8 kf1 = *(const bf16x8*)(kbase + (((4 + lhi) ^ (kr & 7)) << 4));
          z = __builtin_amdgcn_mfma_f32_16x16x32_bf16(kf0, qf[fr][0], z, 0, 0, 0);
          z = __builtin_amdgcn_mfma_f32_16x16x32_bf16(kf1, qf[fr][1], z, 0, 0, 0);
        }
        sf[f] = z;
      }
      __builtin_amdgcn_s_setprio(0);

      if (diag) {
        const int qrow = w * 16 + l15;  // tile-relative (q-tile == kv-tile index)
#pragma unroll
        for (int f = 0; f < 8; ++f)
          if (f <= fE)
#pragma unroll
            for (int r = 0; r < 4; ++r) {
              const int kv = f * 16 + lhi * 4 + r;
              if (kv > qrow) sf[f][r] = -1e30f;
            }
      }

      // row max: in-lane, then combine the 4 lanes sharing this q-row
      float pm = -1e30f;
#pragma unroll
      for (int f = 0; f < 8; ++f)
        if (f <= fE)
#pragma unroll
          for (int r = 0; r < 4; ++r) pm = fmaxf(pm, sf[f][r]);
      pm = fmaxf(pm, __shfl_xor(pm, 16));
      pm = fmaxf(pm, __shfl_xor(pm, 32));

      if (!__all(pm <= mr[fr] + 8.0f)) {  // T13 defer-max
        const float mn = fmaxf(mr[fr], pm);
        const float resc = __builtin_amdgcn_exp2f(mr[fr] - mn);
        mr[fr] = mn;
        lr[fr] *= resc;
#pragma unroll
        for (int r = 0; r < 4; ++r) {
          const float rb = __shfl(resc, (lhi << 2) + r);
#pragma unroll
          for (int df = 0; df < 4; ++df) oa[fr][df][r] *= rb;
        }
      }

      float rs = 0.f;
#pragma unroll
      for (int f = 0; f < 8; ++f)
        if (f <= fE)
#pragma unroll
          for (int r = 0; r < 4; ++r) {
            const float pv = __builtin_amdgcn_exp2f(sf[f][r] - mr[fr]);
            sf[f][r] = pv;
            rs += pv;
          }
      rs += __shfl_xor(rs, 16);
      rs += __shfl_xor(rs, 32);
      lr[fr] += rs;

      // PV: P -> A-fragments in-register (V sigma-permuted to match)
#pragma unroll
      for (int c = 0; c < 4; ++c) {
        if (c <= cE) {
          u32x4 u;
          u.x = cvt_pk_bf16(sf[2 * c][0], sf[2 * c][1]);
          u.y = cvt_pk_bf16(sf[2 * c][2], sf[2 * c][3]);
          u.z = cvt_pk_bf16(sf[2 * c + 1][0], sf[2 * c + 1][1]);
          u.w = cvt_pk_bf16(sf[2 * c + 1][2], sf[2 * c + 1][3]);
          bf16x8 pa = __builtin_bit_cast(bf16x8, u);
          __builtin_amdgcn_s_setprio(1);
#pragma unroll
          for (int df = 0; df < 4; ++df) {
            const int vr = df * 16 + l15;
            bf16x8 vf = *(const bf16x8*)((const char*)lV[cur] + vr * 256 +
                                         ((((c << 2) + lhi) ^ (vr & 15)) << 4));
            oa[fr][df] = __builtin_amdgcn_mfma_f32_16x16x32_bf16(pa, vf, oa[fr][df], 0, 0, 0);
          }
          __builtin_amdgcn_s_setprio(0);
        }
      }
    }

    asm volatile("s_waitcnt vmcnt(0)" ::: "memory");
    __syncthreads();
    cur ^= 1;
  }

  // epilogue: both fragments
#pragma unroll
  for (int fr = 0; fr < 2; ++fr) {
    const int q0 = (fr ? jB : jA) * 128 + w * 16;
    float inv[4];
#pragma unroll
    for (int r = 0; r < 4; ++r)
      inv[r] = __builtin_amdgcn_rcpf(__shfl(lr[fr], (lhi << 2) + r));
#pragma unroll
    for (int df = 0; df < 4; ++df)
#pragma unroll
      for (int r = 0; r < 4; ++r) {
        const int srow_o = q0 + lhi * 4 + r;
        const float val = oa[fr][df][r] * inv[r];
        const int d = df * 16 + l15;
        o[((size_t)(b_out * S_LEN + srow_o)) * DM + h_out * 64 + d] = f2bf(val);
      }
  }
}

extern "C" void kernel_launch(void* const* d_in, const int* in_sizes, int n_in,
                              void* d_out, int out_size, void* d_ws, size_t ws_size,
                              hipStream_t stream) {
  const float* x = (const float*)d_in[0];
  const float* Wq = (const float*)d_in[1];
  const float* Wk = (const float*)d_in[2];
  const float* Wv = (const float*)d_in[3];
  const float* Wo = (const float*)d_in[4];
  const int* pos = (const int*)d_in[5];

  char* ws = (char*)d_ws;
  size_t off = 0;
  auto alloc = [&](size_t bytes) {
    void* p = ws + off;
    off += (bytes + 255) & ~(size_t)255;
    return p;
  };
  uint16_t* xb    = (uint16_t*)alloc((size_t)MTOT * DM * 2);      // also reused as attn output
  uint16_t* wqkvb = (uint16_t*)alloc((size_t)4 * DM * DM * 2);    // contiguous Wq|Wk|Wv|Wo
  uint16_t* qkb   = (uint16_t*)alloc((size_t)2 * MTOT * DM * 2);  // contiguous q|k
  uint16_t* vtb   = (uint16_t*)alloc((size_t)MTOT * DM * 2);      // v, transposed+sigma
  uint16_t* wob = wqkvb + (size_t)3 * DM * DM;
  uint16_t* qb = qkb;
  uint16_t* kbuf = qkb + (size_t)MTOT * DM;
  uint16_t* attnb = xb;  // reuse: x (bf16) dead after QKV projection

  cvt_all<<<768, 256, 0, stream>>>(x, Wq, Wk, Wv, Wo, xb, wqkvb);

  // fused QKV projection + RoPE + V-transpose: N = 3072
  gemm_bt<0, 128><<<dim3(24, MTOT / 128), 256, 0, stream>>>(xb, wqkvb, qkb, vtb, pos);

  attn_kernel<<<dim3(8, 64), 512, 0, stream>>>(qb, kbuf, vtb, attnb);

  // output projection: 128x64 tiles -> 1024 blocks (4/CU) for TLP
  gemm_bt<1, 64><<<dim3(16, MTOT / 128), 256, 0, stream>>>(attnb, wob, d_out, nullptr, nullptr);
}